// Round 5
// baseline (390.715 us; speedup 1.0000x reference)
//
#include <hip/hip_runtime.h>
#include <hip/hip_cooperative_groups.h>

namespace cg = cooperative_groups;

#define NN 2048
#define MLPW 16

typedef __attribute__((ext_vector_type(8))) short short8v;
typedef __attribute__((ext_vector_type(16))) float float16v;
typedef __attribute__((ext_vector_type(4))) unsigned short ushort4v;
typedef __attribute__((ext_vector_type(8))) unsigned short ushort8v;

__device__ __forceinline__ unsigned short f2b(float f) {
  unsigned int u = __float_as_uint(f);
  unsigned int r = (u + 0x7fffu + ((u >> 16) & 1u)) >> 16;  // RNE
  return (unsigned short)r;
}
__device__ __forceinline__ float b2f(unsigned short u) {
  return __uint_as_float(((unsigned int)u) << 16);
}

// ===================== D1: edge MLP + x-cast + Wg1 transpose =================
// blocks [0,2048):    edge MLP row i -> Abf (bf16, +I), dr      (streaming)
// blocks [2048,3072): cast x fp32 -> xb bf16, 2048 elems/block  (streaming)
// blocks [3072,3200): transpose+cast Wg1 [1024][256] -> Wg1T    (streaming)
__global__ void __launch_bounds__(256) edge_kernel(
    const float* __restrict__ adj, const float* __restrict__ xdeg,
    const float* __restrict__ ydeg,
    const float* __restrict__ Wm1, const float* __restrict__ bm1,
    const float* __restrict__ Wm2, const float* __restrict__ bm2,
    const float* __restrict__ x, const float* __restrict__ Wg1,
    unsigned short* __restrict__ Abf, float* __restrict__ dr,
    unsigned short* __restrict__ xb, unsigned short* __restrict__ Wg1T) {
  const int tid = threadIdx.x;
  const int b = blockIdx.x;
  if (b >= 3072) {
    // ---- Wg1^T: [1024][256] fp32 -> [256][1024] bf16
    const int bo = b - 3072;
    const int n = bo * 2 + (tid >> 7);
    const int k0 = (tid & 127) * 8;
    ushort8v o;
#pragma unroll
    for (int e = 0; e < 8; e++) o[e] = f2b(Wg1[(size_t)(k0 + e) * 256 + n]);
    *(ushort8v*)&Wg1T[(size_t)n * 1024 + k0] = o;
    return;
  }
  if (b >= 2048) {
    // ---- x cast fp32 -> bf16
    const size_t idx = (size_t)(b - 2048) * 2048 + (size_t)tid * 8;
    const float4 u = *(const float4*)&x[idx], v = *(const float4*)&x[idx + 4];
    ushort8v o = {f2b(u.x), f2b(u.y), f2b(u.z), f2b(u.w),
                  f2b(v.x), f2b(v.y), f2b(v.z), f2b(v.w)};
    *(ushort8v*)&xb[idx] = o;
    return;
  }
  // ---- edge MLP
  __shared__ float w1[48], b1[16], w2[32], b2s[2];
  __shared__ float wsum[4];
  if (tid < 48) w1[tid] = Wm1[tid];
  if (tid < 16) b1[tid] = bm1[tid];
  if (tid < 32) w2[tid] = Wm2[tid];
  if (tid < 2) b2s[tid] = bm2[tid];
  __syncthreads();
  const int i = b;
  const float4* adj4 = (const float4*)(adj + (size_t)i * NN);
  const float4* xd4 = (const float4*)(xdeg + (size_t)i * NN);
  const float4* yd4 = (const float4*)(ydeg + (size_t)i * NN);
  ushort4v* A4 = (ushort4v*)(Abf + (size_t)i * NN);
  float rsum = 0.f;
  for (int j4 = tid; j4 < NN / 4; j4 += 256) {
    float4 av = adj4[j4], xv = xd4[j4], yv = yd4[j4];
    float aa[4] = {av.x, av.y, av.z, av.w};
    float xx[4] = {xv.x, xv.y, xv.z, xv.w};
    float yy[4] = {yv.x, yv.y, yv.z, yv.w};
    ushort4v oo;
#pragma unroll
    for (int e = 0; e < 4; e++) {
      float l0 = b2s[0], l1 = b2s[1];
#pragma unroll
      for (int k = 0; k < MLPW; k++) {
        float h = fmaf(aa[e], w1[k], fmaf(xx[e], w1[16 + k], fmaf(yy[e], w1[32 + k], b1[k])));
        h = fmaxf(h, 0.f);
        l0 = fmaf(h, w2[2 * k], l0);
        l1 = fmaf(h, w2[2 * k + 1], l1);
      }
      float mask = 1.f / (1.f + __expf(l0 - l1));  // softmax[...,1]
      float v = aa[e] * mask;
      int j = j4 * 4 + e;
      if (j == i) v += 1.f;
      oo[e] = f2b(v);
      rsum += v;
    }
    A4[j4] = oo;
  }
#pragma unroll
  for (int off = 32; off > 0; off >>= 1) rsum += __shfl_down(rsum, off);
  if ((tid & 63) == 0) wsum[tid >> 6] = rsum;
  __syncthreads();
  if (tid == 0) {
    float t = wsum[0] + wsum[1] + wsum[2] + wsum[3];
    dr[i] = t > 0.f ? rsqrtf(t) : 0.f;
  }
}

// ===================== D2: cooperative mega-kernel ===========================
// 512 blocks x 256 threads, phases separated by grid.sync():
//  P1: dc colsum (blocks 0..63)  ||  GEMM1 K-loop, acc in regs (blocks 64..191)
//  P2: GEMM1 epilogue: XWT = bf16(acc * dc[n])
//  P3: GEMM2 split-K SK=8 (all 512 blocks) -> P2 partials
//  P4: tail: T1=dr*sum(P2) -> hid -> HW (blocks 0..255)
//  P5: out[i,:] = dr[i]*(Abf[i,:]@HW)  (4 rows/block)
// LDS: union, max 52224 B (gemm2 tiles) -> 3 blocks/CU >= 2 needed.
__global__ void __launch_bounds__(256, 2) mega_kernel(
    const unsigned short* __restrict__ Abf, const unsigned short* __restrict__ xb,
    const unsigned short* __restrict__ Wg1T, const float* __restrict__ dr,
    float* __restrict__ dc, unsigned short* __restrict__ XWT,
    float* __restrict__ P2, const float* __restrict__ Wl2,
    const float* __restrict__ bl2, const float* __restrict__ Wg2,
    float* __restrict__ hid, float* __restrict__ HW, float* __restrict__ outp) {
  cg::grid_group grid = cg::this_grid();
  __shared__ __align__(16) unsigned char smem[52224];
  constexpr int SW = 136;
  const int tid = threadIdx.x;
  const int bid = blockIdx.x;
  const int lane = tid & 63, wave = tid >> 6;
  const int l31 = lane & 31, half = lane >> 5;

  // ---------------- P1: dc || gemm1 main loop ----------------
  float16v acc1;  // gemm1 accumulator, survives grid.sync to P2
#pragma unroll
  for (int r = 0; r < 16; r++) acc1[r] = 0.f;

  if (bid < 64) {
    // dc colsum: 32 cols per block
    float(*part)[32] = (float(*)[32])smem;
    const int c0 = bid * 32;
    const int cA = (tid & 3) * 8, rgA = tid >> 2;
    float sa[8] = {0, 0, 0, 0, 0, 0, 0, 0};
    const unsigned short* ap = Abf + (size_t)rgA * NN + c0 + cA;
#pragma unroll 4
    for (int k = 0; k < 32; k++) {
      ushort8v u = *(const ushort8v*)ap;
#pragma unroll
      for (int e = 0; e < 8; e++) sa[e] += b2f(u[e]);
      ap += (size_t)64 * NN;
    }
#pragma unroll
    for (int e = 0; e < 8; e++) part[rgA][cA + e] = sa[e];
    __syncthreads();
    if (tid < 32) {
      float d = 0.f;
#pragma unroll
      for (int rg = 0; rg < 64; rg++) d += part[rg][tid];
      dc[c0 + tid] = d > 0.f ? rsqrtf(d) : 0.f;
    }
  } else if (bid < 192) {
    // gemm1: acc = Wg1T[m][:] . xb[n][:], BM=64 x BN=64, K=1024
    unsigned short* As = (unsigned short*)smem;
    unsigned short* Bs = (unsigned short*)(smem + 17408);
    const int g = bid - 64;
    const int row0 = (g >> 5) * 64, col0 = (g & 31) * 64;
    const int mh = wave & 1, nh = wave >> 1;
    for (int k0 = 0; k0 < 1024; k0 += 128) {
#pragma unroll
      for (int i = 0; i < 4; i++) {
        const int id = tid + i * 256;
        const int r = id >> 4, c = id & 15;
        *(ushort8v*)&As[r * SW + c * 8] =
            *(const ushort8v*)&Wg1T[(size_t)(row0 + r) * 1024 + k0 + c * 8];
        *(ushort8v*)&Bs[r * SW + c * 8] =
            *(const ushort8v*)&xb[(size_t)(col0 + r) * 1024 + k0 + c * 8];
      }
      __syncthreads();
#pragma unroll
      for (int ks = 0; ks < 8; ks++) {
        short8v a = *(const short8v*)&As[(mh * 32 + l31) * SW + ks * 16 + half * 8];
        short8v b = *(const short8v*)&Bs[(nh * 32 + l31) * SW + ks * 16 + half * 8];
        acc1 = __builtin_amdgcn_mfma_f32_32x32x16_bf16(a, b, acc1, 0, 0, 0);
      }
      __syncthreads();
    }
  }
  grid.sync();

  // ---------------- P2: gemm1 epilogue (needs dc) ----------------
  if (bid >= 64 && bid < 192) {
    const int g = bid - 64;
    const int row0 = (g >> 5) * 64, col0 = (g & 31) * 64;
    const int mh = wave & 1, nh = wave >> 1;
    const int n = col0 + nh * 32 + l31;
    const float dv = dc[n];
    unsigned short* Xb = XWT + (size_t)(row0 + mh * 32) * NN + n;
#pragma unroll
    for (int reg = 0; reg < 16; reg++) {
      const int m = (reg & 3) + 8 * (reg >> 2) + 4 * half;
      Xb[(size_t)m * NN] = f2b(acc1[reg] * dv);
    }
  }
  grid.sync();

  // ---------------- P3: gemm2 split-K SK=8 (all 512 blocks) ----------------
  {
    unsigned short* As = (unsigned short*)smem;
    unsigned short* Bs = (unsigned short*)(smem + 17408);
    const int sk = bid >> 6;
    const int by = (bid & 63) >> 1, bx = bid & 1;
    const int row0 = by * 64, col0 = bx * 128;
    const int kbeg = sk * 256;
    const int mh = wave & 1, nh = wave >> 1;
    float16v acc0, accb;
#pragma unroll
    for (int r = 0; r < 16; r++) { acc0[r] = 0.f; accb[r] = 0.f; }
    for (int k0 = 0; k0 < 256; k0 += 128) {
#pragma unroll
      for (int i = 0; i < 4; i++) {
        const int id = tid + i * 256;
        const int r = id >> 4, c = id & 15;
        *(ushort8v*)&As[r * SW + c * 8] =
            *(const ushort8v*)&Abf[(size_t)(row0 + r) * NN + kbeg + k0 + c * 8];
      }
#pragma unroll
      for (int i = 0; i < 8; i++) {
        const int id = tid + i * 256;
        const int r = id >> 4, c = id & 15;
        *(ushort8v*)&Bs[r * SW + c * 8] =
            *(const ushort8v*)&XWT[(size_t)(col0 + r) * NN + kbeg + k0 + c * 8];
      }
      __syncthreads();
#pragma unroll
      for (int ks = 0; ks < 8; ks++) {
        short8v a = *(const short8v*)&As[(mh * 32 + l31) * SW + ks * 16 + half * 8];
        short8v b0 = *(const short8v*)&Bs[(nh * 64 + l31) * SW + ks * 16 + half * 8];
        short8v b1 = *(const short8v*)&Bs[(nh * 64 + 32 + l31) * SW + ks * 16 + half * 8];
        acc0 = __builtin_amdgcn_mfma_f32_32x32x16_bf16(a, b0, acc0, 0, 0, 0);
        accb = __builtin_amdgcn_mfma_f32_32x32x16_bf16(a, b1, accb, 0, 0, 0);
      }
      __syncthreads();
    }
    float* Pb = P2 + ((size_t)sk * 2048 + row0 + mh * 32) * 256 + col0 + nh * 64 + l31;
#pragma unroll
    for (int reg = 0; reg < 16; reg++) {
      const int m = (reg & 3) + 8 * (reg >> 2) + 4 * half;
      Pb[(size_t)m * 256] = acc0[reg];
      Pb[(size_t)m * 256 + 32] = accb[reg];
    }
  }
  grid.sync();

  // ---------------- P4: tail (blocks 0..255) ----------------
  if (bid < 256) {
    float(*T1s)[256] = (float(*)[256])smem;
    float(*hidS)[68] = (float(*)[68])(smem + 8192);
    const int m0 = bid * 8;
#pragma unroll
    for (int i = 0; i < 8; i++) {
      const int idx = tid + i * 256;
      const int mi = idx >> 8, n = idx & 255;
      float s = 0.f;
#pragma unroll
      for (int sk = 0; sk < 8; sk++)
        s += P2[((size_t)sk * 2048 + m0 + mi) * 256 + n];
      T1s[mi][n] = s * dr[m0 + mi];
    }
    __syncthreads();
    const int j = tid & 63, mg = tid >> 6;
    float h0 = bl2[j], h1 = h0;
#pragma unroll 8
    for (int n = 0; n < 256; n++) {
      float w = Wl2[(size_t)n * 64 + j];
      h0 = fmaf(T1s[mg * 2 + 0][n], w, h0);
      h1 = fmaf(T1s[mg * 2 + 1][n], w, h1);
    }
    hid[(size_t)(m0 + mg * 2 + 0) * 64 + j] = h0;
    hid[(size_t)(m0 + mg * 2 + 1) * 64 + j] = h1;
    hidS[mg * 2 + 0][j] = h0;
    hidS[mg * 2 + 1][j] = h1;
    __syncthreads();
    if (tid < 32) {
      const int r = tid >> 2, c = tid & 3;
      float s = 0.f;
#pragma unroll
      for (int jj = 0; jj < 64; jj++) s = fmaf(hidS[r][jj], Wg2[jj * 4 + c], s);
      HW[(size_t)(m0 + r) * 4 + c] = s * dc[m0 + r];
    }
  }
  grid.sync();

  // ---------------- P5: out (4 rows per block) ----------------
  {
    float(*wsum)[4] = (float(*)[4])smem;
    const float4* hw4 = (const float4*)HW;
    const int w = tid >> 6;
    const int j0 = tid * 8;
    for (int rr = 0; rr < 4; rr++) {
      const int i = bid * 4 + rr;
      const ushort8v a8 = ((const ushort8v*)(Abf + (size_t)i * NN))[tid];
      float ax = 0.f, ay = 0.f, az = 0.f, aw = 0.f;
#pragma unroll
      for (int e = 0; e < 8; e++) {
        float a = b2f(a8[e]);
        float4 h = hw4[j0 + e];
        ax = fmaf(a, h.x, ax);
        ay = fmaf(a, h.y, ay);
        az = fmaf(a, h.z, az);
        aw = fmaf(a, h.w, aw);
      }
#pragma unroll
      for (int off = 32; off > 0; off >>= 1) {
        ax += __shfl_down(ax, off);
        ay += __shfl_down(ay, off);
        az += __shfl_down(az, off);
        aw += __shfl_down(aw, off);
      }
      if ((tid & 63) == 0) {
        wsum[w][0] = ax; wsum[w][1] = ay; wsum[w][2] = az; wsum[w][3] = aw;
      }
      __syncthreads();
      if (tid < 4)
        outp[(size_t)i * 4 + tid] =
            dr[i] * (wsum[0][tid] + wsum[1][tid] + wsum[2][tid] + wsum[3][tid]);
      __syncthreads();
    }
  }
}

extern "C" void kernel_launch(void* const* d_in, const int* in_sizes, int n_in,
                              void* d_out, int out_size, void* d_ws, size_t ws_size,
                              hipStream_t stream) {
  const float* x    = (const float*)d_in[0];
  const float* adj  = (const float*)d_in[1];
  const float* xdeg = (const float*)d_in[2];
  const float* ydeg = (const float*)d_in[3];
  const float* Wm1  = (const float*)d_in[4];
  const float* bm1  = (const float*)d_in[5];
  const float* Wm2  = (const float*)d_in[6];
  const float* bm2  = (const float*)d_in[7];
  const float* Wg1  = (const float*)d_in[8];
  const float* Wl2  = (const float*)d_in[9];
  const float* bl2  = (const float*)d_in[10];
  const float* Wg2  = (const float*)d_in[11];

  char* ws = (char*)d_ws;
  unsigned short* Abf  = (unsigned short*)(ws);               // 8 MiB [2048][2048]
  unsigned short* xb   = (unsigned short*)(ws + 8388608);     // 4 MiB x bf16
  unsigned short* Wg1T = (unsigned short*)(ws + 12582912);    // 0.5 MiB Wg1^T bf16
  unsigned short* XWT  = (unsigned short*)(ws + 13107200);    // 1 MiB [256][2048]
  float* P2   = (float*)(ws + 14155776);                      // 16 MiB [8][2048][256]
  float* dr   = (float*)(ws + 30932992);
  float* dc   = (float*)(ws + 30941184);
  float* HW   = (float*)(ws + 30949376);                      // 32 KiB

  float* outp = (float*)d_out;             // output 0: [2048,4]
  float* hid  = (float*)d_out + 2048 * 4;  // output 1: [2048,64]

  // D1: edge (2048 blk) + x cast (1024 blk) + Wg1 transpose (128 blk)
  edge_kernel<<<3200, 256, 0, stream>>>(adj, xdeg, ydeg, Wm1, bm1, Wm2, bm2,
                                        x, Wg1, Abf, dr, xb, Wg1T);
  // D2: cooperative mega-kernel: dc || gemm1 -> XWT -> gemm2 -> tail -> out
  void* args[] = {(void*)&Abf, (void*)&xb, (void*)&Wg1T, (void*)&dr,
                  (void*)&dc,  (void*)&XWT, (void*)&P2,  (void*)&Wl2,
                  (void*)&bl2, (void*)&Wg2, (void*)&hid, (void*)&HW,
                  (void*)&outp};
  hipLaunchCooperativeKernel((const void*)mega_kernel, dim3(512), dim3(256),
                             args, 0, stream);
}

// Round 6
// 168.519 us; speedup vs baseline: 2.3185x; 2.3185x over previous
//
#include <hip/hip_runtime.h>

#define NN 2048
#define MLPW 16

typedef __attribute__((ext_vector_type(8))) short short8v;
typedef __attribute__((ext_vector_type(16))) float float16v;
typedef __attribute__((ext_vector_type(4))) unsigned short ushort4v;
typedef __attribute__((ext_vector_type(8))) unsigned short ushort8v;

__device__ __forceinline__ unsigned short f2b(float f) {
  unsigned int u = __float_as_uint(f);
  unsigned int r = (u + 0x7fffu + ((u >> 16) & 1u)) >> 16;  // RNE
  return (unsigned short)r;
}
__device__ __forceinline__ float b2f(unsigned short u) {
  return __uint_as_float(((unsigned int)u) << 16);
}

// ===================== D1: edge MLP + x-cast + Wg1 transpose =================
// blocks [0,2048):    edge MLP row i -> Abf (bf16, +I), dr      (streaming)
// blocks [2048,3072): cast x fp32 -> xb bf16, 2048 elems/block  (streaming)
// blocks [3072,3200): transpose+cast Wg1 [1024][256] -> Wg1T    (streaming)
__global__ void __launch_bounds__(256) edge_kernel(
    const float* __restrict__ adj, const float* __restrict__ xdeg,
    const float* __restrict__ ydeg,
    const float* __restrict__ Wm1, const float* __restrict__ bm1,
    const float* __restrict__ Wm2, const float* __restrict__ bm2,
    const float* __restrict__ x, const float* __restrict__ Wg1,
    unsigned short* __restrict__ Abf, float* __restrict__ dr,
    unsigned short* __restrict__ xb, unsigned short* __restrict__ Wg1T) {
  const int tid = threadIdx.x;
  const int b = blockIdx.x;
  if (b >= 3072) {
    // ---- Wg1^T: [1024][256] fp32 -> [256][1024] bf16
    const int bo = b - 3072;
    const int n = bo * 2 + (tid >> 7);
    const int k0 = (tid & 127) * 8;
    ushort8v o;
#pragma unroll
    for (int e = 0; e < 8; e++) o[e] = f2b(Wg1[(size_t)(k0 + e) * 256 + n]);
    *(ushort8v*)&Wg1T[(size_t)n * 1024 + k0] = o;
    return;
  }
  if (b >= 2048) {
    // ---- x cast fp32 -> bf16
    const size_t idx = (size_t)(b - 2048) * 2048 + (size_t)tid * 8;
    const float4 u = *(const float4*)&x[idx], v = *(const float4*)&x[idx + 4];
    ushort8v o = {f2b(u.x), f2b(u.y), f2b(u.z), f2b(u.w),
                  f2b(v.x), f2b(v.y), f2b(v.z), f2b(v.w)};
    *(ushort8v*)&xb[idx] = o;
    return;
  }
  // ---- edge MLP
  __shared__ float w1[48], b1[16], w2[32], b2s[2];
  __shared__ float wsum[4];
  if (tid < 48) w1[tid] = Wm1[tid];
  if (tid < 16) b1[tid] = bm1[tid];
  if (tid < 32) w2[tid] = Wm2[tid];
  if (tid < 2) b2s[tid] = bm2[tid];
  __syncthreads();
  const int i = b;
  const float4* adj4 = (const float4*)(adj + (size_t)i * NN);
  const float4* xd4 = (const float4*)(xdeg + (size_t)i * NN);
  const float4* yd4 = (const float4*)(ydeg + (size_t)i * NN);
  ushort4v* A4 = (ushort4v*)(Abf + (size_t)i * NN);
  float rsum = 0.f;
  for (int j4 = tid; j4 < NN / 4; j4 += 256) {
    float4 av = adj4[j4], xv = xd4[j4], yv = yd4[j4];
    float aa[4] = {av.x, av.y, av.z, av.w};
    float xx[4] = {xv.x, xv.y, xv.z, xv.w};
    float yy[4] = {yv.x, yv.y, yv.z, yv.w};
    ushort4v oo;
#pragma unroll
    for (int e = 0; e < 4; e++) {
      float l0 = b2s[0], l1 = b2s[1];
#pragma unroll
      for (int k = 0; k < MLPW; k++) {
        float h = fmaf(aa[e], w1[k], fmaf(xx[e], w1[16 + k], fmaf(yy[e], w1[32 + k], b1[k])));
        h = fmaxf(h, 0.f);
        l0 = fmaf(h, w2[2 * k], l0);
        l1 = fmaf(h, w2[2 * k + 1], l1);
      }
      float mask = 1.f / (1.f + __expf(l0 - l1));  // softmax[...,1]
      float v = aa[e] * mask;
      int j = j4 * 4 + e;
      if (j == i) v += 1.f;
      oo[e] = f2b(v);
      rsum += v;
    }
    A4[j4] = oo;
  }
#pragma unroll
  for (int off = 32; off > 0; off >>= 1) rsum += __shfl_down(rsum, off);
  if ((tid & 63) == 0) wsum[tid >> 6] = rsum;
  __syncthreads();
  if (tid == 0) {
    float t = wsum[0] + wsum[1] + wsum[2] + wsum[3];
    dr[i] = t > 0.f ? rsqrtf(t) : 0.f;
  }
}

// ===================== D2: dc = rsqrt(colsum(Abf)) ===========================
// 64 blocks, block owns 32 columns; thread: 8 cols, rows rgA + 64*k.
__global__ void __launch_bounds__(256) dc_kernel(
    const unsigned short* __restrict__ Abf, float* __restrict__ dc) {
  __shared__ float part[64][32];
  const int tid = threadIdx.x;
  const int c0 = blockIdx.x * 32;
  const int cA = (tid & 3) * 8, rgA = tid >> 2;
  float sa[8] = {0, 0, 0, 0, 0, 0, 0, 0};
  const unsigned short* ap = Abf + (size_t)rgA * NN + c0 + cA;
#pragma unroll 4
  for (int k = 0; k < 32; k++) {
    ushort8v u = *(const ushort8v*)ap;
#pragma unroll
    for (int e = 0; e < 8; e++) sa[e] += b2f(u[e]);
    ap += (size_t)64 * NN;
  }
#pragma unroll
  for (int e = 0; e < 8; e++) part[rgA][cA + e] = sa[e];
  __syncthreads();
  if (tid < 32) {
    float d = 0.f;
#pragma unroll
    for (int rg = 0; rg < 64; rg++) d += part[rg][tid];
    dc[c0 + tid] = d > 0.f ? rsqrtf(d) : 0.f;
  }
}

// ===================== D3: GEMM1 direct -> XWT ===============================
// XWT[m][n] = bf16( dc[n] * sum_k Wg1T[m][k] * xb[n][k] )
// BM=64 x BN=64, K=1024 full (no split-K). grid (2048/64=32, 256/64=4).
__global__ void __launch_bounds__(256) gemm1_kernel(
    const unsigned short* __restrict__ A, const unsigned short* __restrict__ B,
    const float* __restrict__ dc, unsigned short* __restrict__ XWT) {
  constexpr int SW = 136;
  __shared__ unsigned short As[64 * SW];
  __shared__ unsigned short Bs[64 * SW];
  const int tid = threadIdx.x;
  const int lane = tid & 63, wave = tid >> 6;
  const int l31 = lane & 31, half = lane >> 5;
  const int mh = wave & 1, nh = wave >> 1;
  const int row0 = blockIdx.y * 64, col0 = blockIdx.x * 64;

  float16v acc;
#pragma unroll
  for (int r = 0; r < 16; r++) acc[r] = 0.f;

  for (int k0 = 0; k0 < 1024; k0 += 128) {
#pragma unroll
    for (int i = 0; i < 4; i++) {
      const int id = tid + i * 256;
      const int r = id >> 4, c = id & 15;
      *(ushort8v*)&As[r * SW + c * 8] =
          *(const ushort8v*)&A[(size_t)(row0 + r) * 1024 + k0 + c * 8];
      *(ushort8v*)&Bs[r * SW + c * 8] =
          *(const ushort8v*)&B[(size_t)(col0 + r) * 1024 + k0 + c * 8];
    }
    __syncthreads();
#pragma unroll
    for (int ks = 0; ks < 8; ks++) {
      short8v a = *(const short8v*)&As[(mh * 32 + l31) * SW + ks * 16 + half * 8];
      short8v b = *(const short8v*)&Bs[(nh * 32 + l31) * SW + ks * 16 + half * 8];
      acc = __builtin_amdgcn_mfma_f32_32x32x16_bf16(a, b, acc, 0, 0, 0);
    }
    __syncthreads();
  }
  // C/D: col = lane&31, row = (reg&3) + 8*(reg>>2) + 4*(lane>>5)
  const int n = col0 + nh * 32 + l31;
  const float dv = dc[n];
  unsigned short* Xb = XWT + (size_t)(row0 + mh * 32) * NN + n;
#pragma unroll
  for (int reg = 0; reg < 16; reg++) {
    const int m = (reg & 3) + 8 * (reg >> 2) + 4 * half;
    Xb[(size_t)m * NN] = f2b(acc[reg] * dv);
  }
}

// ===================== D4: GEMM2 split-K (bf16 x bf16) =======================
// P2[sk][m][n] = sum_{k in chunk} Abf[m][k]*XWT[n][k].  BM=64 x BN=64, KC=256.
// grid (256/64=4, 2048/64=32, 8) = 1024 blocks; LDS 34.8 KB -> 4 blocks/CU
// (vs BN=128's 2/CU): latency-bound kernel, TLP doubled; extra A re-staging is
// free (operands L2/L3-resident).
__global__ void __launch_bounds__(256) gemm2_kernel(
    const unsigned short* __restrict__ A, const unsigned short* __restrict__ B,
    float* __restrict__ P) {
  constexpr int SW = 136;
  __shared__ unsigned short As[64 * SW];
  __shared__ unsigned short Bs[64 * SW];
  const int tid = threadIdx.x;
  const int lane = tid & 63, wave = tid >> 6;
  const int l31 = lane & 31, half = lane >> 5;
  const int mh = wave & 1, nh = wave >> 1;
  const int row0 = blockIdx.y * 64, col0 = blockIdx.x * 64;
  const int kbeg = blockIdx.z * 256;

  float16v acc;
#pragma unroll
  for (int r = 0; r < 16; r++) acc[r] = 0.f;

  for (int k0 = 0; k0 < 256; k0 += 128) {
#pragma unroll
    for (int i = 0; i < 4; i++) {
      const int id = tid + i * 256;
      const int r = id >> 4, c = id & 15;
      *(ushort8v*)&As[r * SW + c * 8] =
          *(const ushort8v*)&A[(size_t)(row0 + r) * NN + kbeg + k0 + c * 8];
      *(ushort8v*)&Bs[r * SW + c * 8] =
          *(const ushort8v*)&B[(size_t)(col0 + r) * NN + kbeg + k0 + c * 8];
    }
    __syncthreads();
#pragma unroll
    for (int ks = 0; ks < 8; ks++) {
      short8v a = *(const short8v*)&As[(mh * 32 + l31) * SW + ks * 16 + half * 8];
      short8v b = *(const short8v*)&Bs[(nh * 32 + l31) * SW + ks * 16 + half * 8];
      acc = __builtin_amdgcn_mfma_f32_32x32x16_bf16(a, b, acc, 0, 0, 0);
    }
    __syncthreads();
  }
  // C/D: col = lane&31, row = (reg&3) + 8*(reg>>2) + 4*(lane>>5)
  float* Pb = P + ((size_t)blockIdx.z * 2048 + row0 + mh * 32) * 256 + col0 + nh * 32 + l31;
#pragma unroll
  for (int reg = 0; reg < 16; reg++) {
    const int m = (reg & 3) + 8 * (reg >> 2) + 4 * half;
    Pb[(size_t)m * 256] = acc[reg];
  }
}

// ===================== D5: fused tail ========================================
// P2 -> T1(=dr*sum) -> hid(@Wl2+bl2) -> HW(=dc*hid@Wg2)
__global__ void __launch_bounds__(256) tail_kernel(
    const float* __restrict__ P2, const float* __restrict__ dr,
    const float* __restrict__ dc, const float* __restrict__ Wl2,
    const float* __restrict__ bl2, const float* __restrict__ Wg2,
    float* __restrict__ hid, float* __restrict__ HW) {
  __shared__ float T1s[8][256];
  __shared__ float hidS[8][68];
  const int m0 = blockIdx.x * 8;
  const int tid = threadIdx.x;
  // phase 1: reduce 8 split-K partials, scale by dr
#pragma unroll
  for (int i = 0; i < 8; i++) {
    const int idx = tid + i * 256;
    const int mi = idx >> 8, n = idx & 255;
    float s = 0.f;
#pragma unroll
    for (int sk = 0; sk < 8; sk++)
      s += P2[((size_t)sk * 2048 + m0 + mi) * 256 + n];
    T1s[mi][n] = s * dr[m0 + mi];
  }
  __syncthreads();
  // phase 2: hid[m][j] = T1[m][:] @ Wl2[:,j] + bl2[j]
  const int j = tid & 63, mg = tid >> 6;
  float h0 = bl2[j], h1 = h0;
#pragma unroll 8
  for (int n = 0; n < 256; n++) {
    float w = Wl2[(size_t)n * 64 + j];
    h0 = fmaf(T1s[mg * 2 + 0][n], w, h0);
    h1 = fmaf(T1s[mg * 2 + 1][n], w, h1);
  }
  hid[(size_t)(m0 + mg * 2 + 0) * 64 + j] = h0;
  hid[(size_t)(m0 + mg * 2 + 1) * 64 + j] = h1;
  hidS[mg * 2 + 0][j] = h0;
  hidS[mg * 2 + 1][j] = h1;
  __syncthreads();
  // phase 3: HW[m][c] = dc[m] * hid[m][:] @ Wg2[:,c]
  if (tid < 32) {
    const int r = tid >> 2, c = tid & 3;
    float s = 0.f;
#pragma unroll
    for (int jj = 0; jj < 64; jj++) s = fmaf(hidS[r][jj], Wg2[jj * 4 + c], s);
    HW[(size_t)(m0 + r) * 4 + c] = s * dc[m0 + r];
  }
}

// ===================== D6: out[i,:] = dr[i] * (Abf[i,:] @ HW) ================
__global__ void __launch_bounds__(256) out_kernel(
    const unsigned short* __restrict__ Abf, const float* __restrict__ HW,
    const float* __restrict__ dr, float* __restrict__ outp) {
  const int i = blockIdx.x, tid = threadIdx.x;
  const ushort8v a8 = ((const ushort8v*)(Abf + (size_t)i * NN))[tid];
  const float4* hw4 = (const float4*)HW;
  const int j0 = tid * 8;
  float ax = 0.f, ay = 0.f, az = 0.f, aw = 0.f;
#pragma unroll
  for (int e = 0; e < 8; e++) {
    float a = b2f(a8[e]);
    float4 h = hw4[j0 + e];
    ax = fmaf(a, h.x, ax);
    ay = fmaf(a, h.y, ay);
    az = fmaf(a, h.z, az);
    aw = fmaf(a, h.w, aw);
  }
#pragma unroll
  for (int off = 32; off > 0; off >>= 1) {
    ax += __shfl_down(ax, off);
    ay += __shfl_down(ay, off);
    az += __shfl_down(az, off);
    aw += __shfl_down(aw, off);
  }
  __shared__ float wsum[4][4];
  const int w = tid >> 6;
  if ((tid & 63) == 0) {
    wsum[w][0] = ax; wsum[w][1] = ay; wsum[w][2] = az; wsum[w][3] = aw;
  }
  __syncthreads();
  if (tid < 4)
    outp[(size_t)i * 4 + tid] =
        dr[i] * (wsum[0][tid] + wsum[1][tid] + wsum[2][tid] + wsum[3][tid]);
}

extern "C" void kernel_launch(void* const* d_in, const int* in_sizes, int n_in,
                              void* d_out, int out_size, void* d_ws, size_t ws_size,
                              hipStream_t stream) {
  const float* x    = (const float*)d_in[0];
  const float* adj  = (const float*)d_in[1];
  const float* xdeg = (const float*)d_in[2];
  const float* ydeg = (const float*)d_in[3];
  const float* Wm1  = (const float*)d_in[4];
  const float* bm1  = (const float*)d_in[5];
  const float* Wm2  = (const float*)d_in[6];
  const float* bm2  = (const float*)d_in[7];
  const float* Wg1  = (const float*)d_in[8];
  const float* Wl2  = (const float*)d_in[9];
  const float* bl2  = (const float*)d_in[10];
  const float* Wg2  = (const float*)d_in[11];

  char* ws = (char*)d_ws;
  unsigned short* Abf  = (unsigned short*)(ws);               // 8 MiB [2048][2048]
  unsigned short* xb   = (unsigned short*)(ws + 8388608);     // 4 MiB x bf16
  unsigned short* Wg1T = (unsigned short*)(ws + 12582912);    // 0.5 MiB Wg1^T bf16
  unsigned short* XWT  = (unsigned short*)(ws + 13107200);    // 1 MiB [256][2048]
  float* P2   = (float*)(ws + 14155776);                      // 16 MiB [8][2048][256]
  float* dr   = (float*)(ws + 30932992);
  float* dc   = (float*)(ws + 30941184);
  float* HW   = (float*)(ws + 30949376);                      // 32 KiB

  float* outp = (float*)d_out;             // output 0: [2048,4]
  float* hid  = (float*)d_out + 2048 * 4;  // output 1: [2048,64]

  // D1: edge (2048 blk) + x cast (1024 blk) + Wg1 transpose (128 blk)
  edge_kernel<<<3200, 256, 0, stream>>>(adj, xdeg, ydeg, Wm1, bm1, Wm2, bm2,
                                        x, Wg1, Abf, dr, xb, Wg1T);
  // D2: colsum -> dc
  dc_kernel<<<64, 256, 0, stream>>>(Abf, dc);
  // D3: GEMM1 full-K, dc+bf16 epilogue -> XWT (no partials)
  gemm1_kernel<<<dim3(2048 / 64, 256 / 64), 256, 0, stream>>>(Wg1T, xb, dc, XWT);
  // D4: GEMM2  P2[sk][m][n] partial of Abf @ XWT^T (M=2048, N=256, K=2048, SK=8)
  gemm2_kernel<<<dim3(256 / 64, 2048 / 64, 8), 256, 0, stream>>>(Abf, XWT, P2);
  // D5: tail -> hid, HW
  tail_kernel<<<2048 / 8, 256, 0, stream>>>(P2, dr, dc, Wl2, bl2, Wg2, hid, HW);
  // D6: out
  out_kernel<<<NN, 256, 0, stream>>>(Abf, HW, dr, outp);
}